// Round 11
// baseline (1004.750 us; speedup 1.0000x reference)
//
#include <hip/hip_runtime.h>
#include <hip/hip_bf16.h>
#include <math.h>

typedef __attribute__((ext_vector_type(8))) __bf16 bf16x8;
typedef __attribute__((ext_vector_type(4))) float f32x4;
typedef __attribute__((ext_vector_type(4))) int i32x4;

// ---- sort configuration ---------------------------------------------------
#define NBUCKET 512            // 8x8x8 regions of 16^3 cells
#define HB      256            // histogram blocks
// workspace layout (bytes) -- perm-only sort (no coord/ray staging)
#define WS_WP   0UL                    // packed weights     32 KB
#define WS_MAT  32768UL                // [HB][NBUCKET] u32  512 KB
#define WS_TOT  557056UL               // 512 u32
#define WS_BB   559104UL               // 512 u32
#define WS_PERM 561152UL               // perm[N]             8 MB
#define WS_NEED 8949760UL

// ---------------------------------------------------------------------------
// Pack MLP weights into MFMA A-fragment layout (weights-as-A).
// Frag f: 1024 B; lane l supplies A[m = l&15][kpos = (l>>4)*8 + j].
//   frags 0-7  : wd1, K-order identity          (out-frag n)
//   frags 8-11 : wd2, K-order PERMUTED          (K-tile kt)
//   frags 12-27: wc1, K-order = F-layout        (out-frag f3, kt3 = frag&1)
//   frags 28-31: wc2, K-order PERMUTED          (K-tile kt)
// PERMUTED K-row for (kt,kg,j): row = 32kt + 16(j>>2) + 4kg + (j&3) --
// makes the previous layer's D-layout directly usable as B-fragments.
// F-layout rows (L3): kt3=0,j<4 -> dfeat 4kg+j ; kt3=0,j>=4 -> view
// 16+4kg+(j-4) ; kt3=1 -> view 32+8kg+j (rows >42 zero).
// ---------------------------------------------------------------------------
__global__ void pack_weights(const float* __restrict__ wd1,
                             const float* __restrict__ wd2,
                             const float* __restrict__ wc1,
                             const float* __restrict__ wc2,
                             __bf16* __restrict__ wp)
{
    int t0 = threadIdx.x;
    for (int it = 0; it < 8; ++it) {
        int t = it * 256 + t0;
        int frag = t >> 6;
        int lane = t & 63;
        int kg = lane >> 4;
        int c  = lane & 15;
        for (int j = 0; j < 8; ++j) {
            float v;
            if (frag < 8) {
                int k = kg * 8 + j;
                v = wd1[k * 128 + frag * 16 + c];
            } else if (frag < 12) {
                int kt = frag - 8;
                int row = 32 * kt + 16 * (j >> 2) + 4 * kg + (j & 3);
                v = wd2[row * 16 + c];
            } else if (frag < 28) {
                int f = frag - 12;
                int f3 = f >> 1, kt3 = f & 1;
                int row;
                if (kt3 == 0) row = (j < 4) ? (4 * kg + j) : (16 + 4 * kg + (j - 4));
                else          row = 32 + 8 * kg + j;
                v = (row < 43) ? wc1[row * 128 + f3 * 16 + c] : 0.0f;
            } else {
                int kt = frag - 28;
                int row = 32 * kt + 16 * (j >> 2) + 4 * kg + (j & 3);
                v = (c < 3) ? wc2[row * 3 + c] : 0.0f;
            }
            wp[frag * 512 + lane * 8 + j] = (__bf16)v;
        }
    }
}

__device__ __forceinline__ int bucket_key(float x, float y, float z) {
    int ix = (int)(x * 127.0f); ix = ix < 0 ? 0 : (ix > 127 ? 127 : ix);
    int iy = (int)(y * 127.0f); iy = iy < 0 ? 0 : (iy > 127 ? 127 : iy);
    int iz = (int)(z * 127.0f); iz = iz < 0 ? 0 : (iz > 127 ? 127 : iz);
    return ((ix >> 4) << 6) | ((iy >> 4) << 3) | (iz >> 4);
}

__global__ __launch_bounds__(256) void hist_lds(const float* __restrict__ coords,
                                                unsigned int* __restrict__ mat,
                                                int ppb)
{
    __shared__ unsigned int lh[NBUCKET];
    for (int i = threadIdx.x; i < NBUCKET; i += 256) lh[i] = 0u;
    __syncthreads();
    int base = blockIdx.x * ppb;
    for (int k = threadIdx.x; k < ppb; k += 256) {
        size_t b = 3 * (size_t)(base + k);
        atomicAdd(&lh[bucket_key(coords[b], coords[b + 1], coords[b + 2])], 1u);
    }
    __syncthreads();
    unsigned int* row = mat + (size_t)blockIdx.x * NBUCKET;
    for (int i = threadIdx.x; i < NBUCKET; i += 256) row[i] = lh[i];
}

__global__ __launch_bounds__(256) void col_scan(unsigned int* __restrict__ mat,
                                                unsigned int* __restrict__ total)
{
    int wid  = threadIdx.x >> 6;
    int lane = threadIdx.x & 63;
    int bkt  = blockIdx.x * 4 + wid;

    unsigned int v[4];
#pragma unroll
    for (int j = 0; j < 4; ++j)
        v[j] = mat[(size_t)(lane * 4 + j) * NBUCKET + bkt];
    unsigned int pre[4];
    unsigned int sum = 0;
#pragma unroll
    for (int j = 0; j < 4; ++j) { pre[j] = sum; sum += v[j]; }
    unsigned int inc = sum;
    for (int d = 1; d < 64; d <<= 1) {
        unsigned int u = __shfl_up(inc, d);
        if (lane >= d) inc += u;
    }
    unsigned int excl = inc - sum;
#pragma unroll
    for (int j = 0; j < 4; ++j)
        mat[(size_t)(lane * 4 + j) * NBUCKET + bkt] = excl + pre[j];
    if (lane == 63) total[bkt] = inc;
}

__global__ __launch_bounds__(256) void bucket_scan(const unsigned int* __restrict__ total,
                                                   unsigned int* __restrict__ bbase)
{
    int t = threadIdx.x;
    unsigned int v0 = total[2 * t], v1 = total[2 * t + 1];
    unsigned int run = v0 + v1;
    unsigned int lane = t & 63;
    int wid = t >> 6;
    unsigned int inc = run;
    for (int d = 1; d < 64; d <<= 1) {
        unsigned int u = __shfl_up(inc, d);
        if (lane >= (unsigned)d) inc += u;
    }
    __shared__ unsigned int wt[4];
    if (lane == 63) wt[wid] = inc;
    __syncthreads();
    unsigned int wbase = 0;
    for (int w = 0; w < wid; ++w) wbase += wt[w];
    unsigned int excl = wbase + inc - run;
    bbase[2 * t]     = excl;
    bbase[2 * t + 1] = excl + v0;
}

// scatter: writes ONLY perm (sorted slot -> original index). 8 MB output.
__global__ __launch_bounds__(256) void scatter_perm(const float* __restrict__ coords,
                                                    const unsigned int* __restrict__ mat,
                                                    const unsigned int* __restrict__ bbase,
                                                    int* __restrict__ perm,
                                                    int ppb)
{
    __shared__ unsigned int cur[NBUCKET];
    const unsigned int* row = mat + (size_t)blockIdx.x * NBUCKET;
    for (int i = threadIdx.x; i < NBUCKET; i += 256)
        cur[i] = bbase[i] + row[i];
    __syncthreads();
    int base = blockIdx.x * ppb;
    for (int k = threadIdx.x; k < ppb; k += 256) {
        int i = base + k;
        size_t b = 3 * (size_t)i;
        unsigned int dst = atomicAdd(&cur[bucket_key(coords[b], coords[b + 1], coords[b + 2])], 1u);
        perm[dst] = i;
    }
}

// ---------------------------------------------------------------------------
// Fused NeRF forward: weights-as-A / activations-as-B with co-designed
// K-order packings (all inter-layer handoffs are LOCAL registers).
// 1024-thread blocks (16 waves) share ONE 32 KB LDS weight copy ->
// 2 blocks/CU x 16 waves = 32 waves/CU (100% occupancy cap).
// coords/ray via perm indirection, 2-deep perm / 1-deep coord pipeline.
// ---------------------------------------------------------------------------
__device__ __forceinline__ unsigned int pack2(float a, float b) {
    union { __bf16 h[2]; unsigned int u; } x;
    x.h[0] = (__bf16)a; x.h[1] = (__bf16)b;
    return x.u;
}

union BFU { bf16x8 v; unsigned int u[4]; };

template <bool SORTED>
__global__ __launch_bounds__(1024)
__attribute__((amdgpu_waves_per_eu(8)))
void nerf_wave(const float* __restrict__ coords,   // ORIGINAL order
               const float* __restrict__ ray_d,    // ORIGINAL order
               const float* __restrict__ grid,     // [128][128][128][32] f32
               const float* __restrict__ bd1,
               const float* __restrict__ bd2,
               const float* __restrict__ bc1,
               const float* __restrict__ bc2,
               const __bf16* __restrict__ wp,
               const int* __restrict__ perm,       // sorted slot -> original
               float* __restrict__ out,            // [N][4]
               int nbt)                            // number of 256-pt tiles
{
    // LDS: [0,32K) all 32 weight frags (block-shared); then bias tables.
    __shared__ __align__(16) char lds[32768 + 1152];
    float* ldsB1 = (float*)(lds + 32768);   // bd1[128]
    float* ldsB2 = ldsB1 + 128;             // bd2[16]
    float* ldsB3 = ldsB2 + 16;              // bc1[128]
    float* ldsB4 = ldsB3 + 128;             // bc2 padded[16]

    const int tid = threadIdx.x;
    {
        const i32x4* src = (const i32x4*)wp;
        i32x4* dst = (i32x4*)lds;
        for (int i = tid; i < 2048; i += 1024) dst[i] = src[i];
        if (tid < 128) ldsB1[tid] = bd1[tid];
        else if (tid < 144) ldsB2[tid - 128] = bd2[tid - 128];
        else if (tid < 272) ldsB3[tid - 144] = bc1[tid - 144];
        else if (tid < 288) ldsB4[tid - 272] = (tid - 272 < 3) ? bc2[tid - 272] : 0.0f;
    }
    __syncthreads();   // only barrier in the kernel

    const int lane = tid & 63;
    const int wid  = tid >> 6;             // 0..15
    const int c    = lane & 15;
    const int kg   = lane >> 4;
    const int lb   = lane * 16;            // byte offset of lane's frag row
    const int q3   = lane / 3;             // point index for coord loads
    const int e3   = lane - 3 * q3;        // element (x/y/z)

    const int per = (nbt + gridDim.x - 1) / gridDim.x;
    int sb = blockIdx.x;
    if ((gridDim.x & 7) == 0)
        sb = (blockIdx.x & 7) * (gridDim.x >> 3) + (blockIdx.x >> 3);

    // ---- pipeline prologue -------------------------------------------------
    int t0 = sb * per;       if (t0 >= nbt) t0 = nbt - 1;
    int t1 = sb * per + 1;   if (t1 >= nbt) t1 = nbt - 1;
    int pvA, pvB;            // perm of this lane's point c, iters it / it+1
    if constexpr (SORTED) pvA = perm[t0 * 256 + wid * 16 + c];
    else                  pvA = t0 * 256 + wid * 16 + c;
    int pq0 = __shfl(pvA, q3);
    float cvalA = (lane < 48) ? coords[(size_t)pq0 * 3 + e3] : 0.0f;
    float rvalA = (lane < 48) ? ray_d[(size_t)pq0 * 3 + e3] : 0.0f;
    if constexpr (SORTED) pvB = perm[t1 * 256 + wid * 16 + c];
    else                  pvB = t1 * 256 + wid * 16 + c;

    for (int it = 0; it < per; ++it) {
        const int tile = sb * per + it;
        if (tile >= nbt) break;

        // ---- coords of this lane's point c (from pipelined cvalA) ---------
        float cx = __shfl(cvalA, 3 * c + 0) * 127.0f;
        float cy = __shfl(cvalA, 3 * c + 1) * 127.0f;
        float cz = __shfl(cvalA, 3 * c + 2) * 127.0f;
        int ix = (int)floorf(cx); ix = ix < 0 ? 0 : (ix > 126 ? 126 : ix);
        int iy = (int)floorf(cy); iy = iy < 0 ? 0 : (iy > 126 ? 126 : iy);
        int iz = (int)floorf(cz); iz = iz < 0 ? 0 : (iz > 126 ? 126 : iz);
        float tx = cx - (float)ix;
        float ty = cy - (float)iy;
        float tz = cz - (float)iz;

        // ---- gather: feats[kg*8 .. kg*8+7] of point c (B-frag layout) -----
        f32x4 fa = {0.0f, 0.0f, 0.0f, 0.0f};
        f32x4 fb = {0.0f, 0.0f, 0.0f, 0.0f};
#pragma unroll
        for (int cc = 0; cc < 8; ++cc) {
            int ddx = (cc >> 2) & 1, ddy = (cc >> 1) & 1, ddz = cc & 1;
            float w = (ddx ? tx : 1.0f - tx) *
                      (ddy ? ty : 1.0f - ty) *
                      (ddz ? tz : 1.0f - tz);
            int idx = ((ix + ddx) << 14) + ((iy + ddy) << 7) + (iz + ddz);
            const f32x4* g = (const f32x4*)(grid + (size_t)idx * 32 + kg * 8);
            f32x4 v0 = g[0], v1 = g[1];
#pragma unroll
            for (int e = 0; e < 4; ++e) {
                fa[e] = fmaf(w, v0[e], fa[e]);
                fb[e] = fmaf(w, v1[e], fb[e]);
            }
        }
        BFU b0;
        b0.u[0] = pack2(fa[0], fa[1]); b0.u[1] = pack2(fa[2], fa[3]);
        b0.u[2] = pack2(fb[0], fb[1]); b0.u[3] = pack2(fb[2], fb[3]);

        // ---- prefetch next iteration (overlaps the MLP below) -------------
        float cvalN, rvalN;
        int pvC;
        {
            int pqn = __shfl(pvB, q3);          // pvB loaded last iteration
            cvalN = (lane < 48) ? coords[(size_t)pqn * 3 + e3] : 0.0f;
            rvalN = (lane < 48) ? ray_d[(size_t)pqn * 3 + e3] : 0.0f;
            int t2 = tile + 2; if (t2 >= nbt) t2 = nbt - 1;
            if constexpr (SORTED) pvC = perm[t2 * 256 + wid * 16 + c];
            else                  pvC = t2 * 256 + wid * 16 + c;
        }

        // ---- view embedding slots for this lane (dims fixed by kg) --------
        float dxv = __shfl(rvalA, 3 * c + 0);
        float dyv = __shfl(rvalA, 3 * c + 1);
        float dzv = __shfl(rvalA, 3 * c + 2);
        float E0, E1, E2, E3, G0, G1, G2, G3, G4, G5, G6, G7;
        if (kg == 0) {            // E: dims 16-19, G: dims 32-39
            E0 = dxv; E1 = dyv; E2 = dzv; E3 = __sinf(dxv);
            G0 = __cosf(dyv);        G1 = __cosf(dzv);
            G2 = __cosf(2.0f * dxv); G3 = __cosf(2.0f * dyv);
            G4 = __cosf(2.0f * dzv); G5 = __cosf(4.0f * dxv);
            G6 = __cosf(4.0f * dyv); G7 = __cosf(4.0f * dzv);
        } else if (kg == 1) {     // E: dims 20-23, G: dims 40-42 + zeros
            E0 = __sinf(dyv);        E1 = __sinf(dzv);
            E2 = __sinf(2.0f * dxv); E3 = __sinf(2.0f * dyv);
            G0 = __cosf(8.0f * dxv); G1 = __cosf(8.0f * dyv);
            G2 = __cosf(8.0f * dzv);
            G3 = 0.0f; G4 = 0.0f; G5 = 0.0f; G6 = 0.0f; G7 = 0.0f;
        } else if (kg == 2) {     // E: dims 24-27, G: zeros
            E0 = __sinf(2.0f * dzv); E1 = __sinf(4.0f * dxv);
            E2 = __sinf(4.0f * dyv); E3 = __sinf(4.0f * dzv);
            G0 = G1 = G2 = G3 = G4 = G5 = G6 = G7 = 0.0f;
        } else {                  // E: dims 28-31, G: zeros
            E0 = __sinf(8.0f * dxv); E1 = __sinf(8.0f * dyv);
            E2 = __sinf(8.0f * dzv); E3 = __cosf(dxv);
            G0 = G1 = G2 = G3 = G4 = G5 = G6 = G7 = 0.0f;
        }

        // ---- L1: h[16n+4kg+i][c] = wd1^T . feats + bd1 --------------------
        f32x4 acc[8];
#pragma unroll
        for (int n = 0; n < 8; ++n) {
            f32x4 bi = *(const f32x4*)(ldsB1 + n * 16 + kg * 4);
            bf16x8 A = *(const bf16x8*)(lds + n * 1024 + lb);
            acc[n] = __builtin_amdgcn_mfma_f32_16x16x32_bf16(A, b0.v, bi, 0, 0, 0);
        }
        unsigned int pk[8][2];
#pragma unroll
        for (int n = 0; n < 8; ++n) {
            pk[n][0] = pack2(fmaxf(acc[n][0], 0.0f), fmaxf(acc[n][1], 0.0f));
            pk[n][1] = pack2(fmaxf(acc[n][2], 0.0f), fmaxf(acc[n][3], 0.0f));
        }

        // ---- L2: dfeat[4kg+i][c]; split into 2 parallel chains ------------
        f32x4 a2A = *(const f32x4*)(ldsB2 + kg * 4);
        f32x4 a2B = {0.0f, 0.0f, 0.0f, 0.0f};
#pragma unroll
        for (int kt = 0; kt < 4; ++kt) {
            BFU B;
            B.u[0] = pk[2 * kt][0];     B.u[1] = pk[2 * kt][1];
            B.u[2] = pk[2 * kt + 1][0]; B.u[3] = pk[2 * kt + 1][1];
            bf16x8 A = *(const bf16x8*)(lds + (8 + kt) * 1024 + lb);
            if (kt & 1) a2B = __builtin_amdgcn_mfma_f32_16x16x32_bf16(A, B.v, a2B, 0, 0, 0);
            else        a2A = __builtin_amdgcn_mfma_f32_16x16x32_bf16(A, B.v, a2A, 0, 0, 0);
        }
        f32x4 accd = a2A + a2B;
        float dens = fmaxf(accd[0], 0.0f);   // dfeat[0]: valid on kg==0 lanes

        // ---- L3: B(kt3=0) = {dfeat local, E}, B(kt3=1) = {G} --------------
        BFU Bk0, Bk1;
        Bk0.u[0] = pack2(accd[0], accd[1]);
        Bk0.u[1] = pack2(accd[2], accd[3]);
        Bk0.u[2] = pack2(E0, E1);
        Bk0.u[3] = pack2(E2, E3);
        Bk1.u[0] = pack2(G0, G1);
        Bk1.u[1] = pack2(G2, G3);
        Bk1.u[2] = pack2(G4, G5);
        Bk1.u[3] = pack2(G6, G7);

        f32x4 acc3[8];
#pragma unroll
        for (int n = 0; n < 8; ++n) {
            f32x4 bi = *(const f32x4*)(ldsB3 + n * 16 + kg * 4);
            bf16x8 w0 = *(const bf16x8*)(lds + (12 + n * 2 + 0) * 1024 + lb);
            bf16x8 w1 = *(const bf16x8*)(lds + (12 + n * 2 + 1) * 1024 + lb);
            acc3[n] = __builtin_amdgcn_mfma_f32_16x16x32_bf16(w0, Bk0.v, bi, 0, 0, 0);
            acc3[n] = __builtin_amdgcn_mfma_f32_16x16x32_bf16(w1, Bk1.v, acc3[n], 0, 0, 0);
        }
        unsigned int pk3[8][2];
#pragma unroll
        for (int n = 0; n < 8; ++n) {
            pk3[n][0] = pack2(fmaxf(acc3[n][0], 0.0f), fmaxf(acc3[n][1], 0.0f));
            pk3[n][1] = pack2(fmaxf(acc3[n][2], 0.0f), fmaxf(acc3[n][3], 0.0f));
        }

        // ---- L4: rgb[4kg+i][c]; split into 2 parallel chains --------------
        f32x4 a4A = *(const f32x4*)(ldsB4 + kg * 4);
        f32x4 a4B = {0.0f, 0.0f, 0.0f, 0.0f};
#pragma unroll
        for (int kt = 0; kt < 4; ++kt) {
            BFU B;
            B.u[0] = pk3[2 * kt][0];     B.u[1] = pk3[2 * kt][1];
            B.u[2] = pk3[2 * kt + 1][0]; B.u[3] = pk3[2 * kt + 1][1];
            bf16x8 A = *(const bf16x8*)(lds + (28 + kt) * 1024 + lb);
            if (kt & 1) a4B = __builtin_amdgcn_mfma_f32_16x16x32_bf16(A, B.v, a4B, 0, 0, 0);
            else        a4A = __builtin_amdgcn_mfma_f32_16x16x32_bf16(A, B.v, a4A, 0, 0, 0);
        }
        f32x4 acco = a4A + a4B;

        // ---- store: lane (kg==0, c) owns point c completely ---------------
        if (lane < 16) {
            f32x4 o;
            o[0] = 1.0f / (1.0f + __expf(-acco[0]));
            o[1] = 1.0f / (1.0f + __expf(-acco[1]));
            o[2] = 1.0f / (1.0f + __expf(-acco[2]));
            o[3] = dens;
            ((f32x4*)out)[pvA] = o;
        }

        // ---- rotate pipeline ----------------------------------------------
        cvalA = cvalN; rvalA = rvalN;
        pvA = pvB; pvB = pvC;
    }
}

extern "C" void kernel_launch(void* const* d_in, const int* in_sizes, int n_in,
                              void* d_out, int out_size, void* d_ws, size_t ws_size,
                              hipStream_t stream) {
    const float* coords = (const float*)d_in[0];
    const float* ray_d  = (const float*)d_in[1];
    const float* grid   = (const float*)d_in[2];
    const float* wd1    = (const float*)d_in[3];
    const float* bd1    = (const float*)d_in[4];
    const float* wd2    = (const float*)d_in[5];
    const float* bd2    = (const float*)d_in[6];
    const float* wc1    = (const float*)d_in[7];
    const float* bc1    = (const float*)d_in[8];
    const float* wc2    = (const float*)d_in[9];
    const float* bc2    = (const float*)d_in[10];
    float* out = (float*)d_out;

    int N = in_sizes[0] / 3;
    int nbt = N >> 8;                       // 256-point tiles

    char* ws = (char*)d_ws;
    __bf16* wp = (__bf16*)(ws + WS_WP);

    pack_weights<<<1, 256, 0, stream>>>(wd1, wd2, wc1, wc2, wp);

    int blocks = nbt < 2048 ? nbt : 2048;

    if (ws_size >= WS_NEED && (N % (HB * 256)) == 0) {
        unsigned int* mat   = (unsigned int*)(ws + WS_MAT);
        unsigned int* total = (unsigned int*)(ws + WS_TOT);
        unsigned int* bbase = (unsigned int*)(ws + WS_BB);
        int* perm = (int*)(ws + WS_PERM);
        int ppb = N / HB;

        hist_lds<<<HB, 256, 0, stream>>>(coords, mat, ppb);
        col_scan<<<NBUCKET / 4, 256, 0, stream>>>(mat, total);
        bucket_scan<<<1, 256, 0, stream>>>(total, bbase);
        scatter_perm<<<HB, 256, 0, stream>>>(coords, mat, bbase, perm, ppb);
        nerf_wave<true><<<blocks, 1024, 0, stream>>>(coords, ray_d, grid,
                                                     bd1, bd2, bc1, bc2,
                                                     wp, perm, out, nbt);
    } else {
        nerf_wave<false><<<blocks, 1024, 0, stream>>>(coords, ray_d, grid,
                                                      bd1, bd2, bc1, bc2,
                                                      wp, nullptr, out, nbt);
    }
}

// Round 12
// 403.692 us; speedup vs baseline: 2.4889x; 2.4889x over previous
//
#include <hip/hip_runtime.h>
#include <hip/hip_bf16.h>
#include <math.h>

typedef __attribute__((ext_vector_type(8))) __bf16 bf16x8;
typedef __attribute__((ext_vector_type(4))) float f32x4;
typedef __attribute__((ext_vector_type(4))) int i32x4;

// ---- sort configuration ---------------------------------------------------
#define NBUCKET 512            // 8x8x8 regions of 16^3 cells
#define HB      256            // histogram blocks
// workspace layout (bytes) -- perm-only sort (no coord/ray staging)
#define WS_WP   0UL                    // packed weights     32 KB
#define WS_MAT  32768UL                // [HB][NBUCKET] u32  512 KB
#define WS_TOT  557056UL               // 512 u32
#define WS_BB   559104UL               // 512 u32
#define WS_PERM 561152UL               // perm[N]             8 MB
#define WS_NEED 8949760UL

// ---------------------------------------------------------------------------
// Pack MLP weights into MFMA A-fragment layout (weights-as-A).
// Frag f: 1024 B; lane l supplies A[m = l&15][kpos = (l>>4)*8 + j].
//   frags 0-7  : wd1, K-order identity          (out-frag n)
//   frags 8-11 : wd2, K-order PERMUTED          (K-tile kt)
//   frags 12-27: wc1, K-order = F-layout        (out-frag f3, kt3 = frag&1)
//   frags 28-31: wc2, K-order PERMUTED          (K-tile kt)
// PERMUTED K-row for (kt,kg,j): row = 32kt + 16(j>>2) + 4kg + (j&3) --
// makes the previous layer's D-layout directly usable as B-fragments.
// F-layout rows (L3): kt3=0,j<4 -> dfeat 4kg+j ; kt3=0,j>=4 -> view
// 16+4kg+(j-4) ; kt3=1 -> view 32+8kg+j (rows >42 zero).
// ---------------------------------------------------------------------------
__global__ void pack_weights(const float* __restrict__ wd1,
                             const float* __restrict__ wd2,
                             const float* __restrict__ wc1,
                             const float* __restrict__ wc2,
                             __bf16* __restrict__ wp)
{
    int t0 = threadIdx.x;
    for (int it = 0; it < 8; ++it) {
        int t = it * 256 + t0;
        int frag = t >> 6;
        int lane = t & 63;
        int kg = lane >> 4;
        int c  = lane & 15;
        for (int j = 0; j < 8; ++j) {
            float v;
            if (frag < 8) {
                int k = kg * 8 + j;
                v = wd1[k * 128 + frag * 16 + c];
            } else if (frag < 12) {
                int kt = frag - 8;
                int row = 32 * kt + 16 * (j >> 2) + 4 * kg + (j & 3);
                v = wd2[row * 16 + c];
            } else if (frag < 28) {
                int f = frag - 12;
                int f3 = f >> 1, kt3 = f & 1;
                int row;
                if (kt3 == 0) row = (j < 4) ? (4 * kg + j) : (16 + 4 * kg + (j - 4));
                else          row = 32 + 8 * kg + j;
                v = (row < 43) ? wc1[row * 128 + f3 * 16 + c] : 0.0f;
            } else {
                int kt = frag - 28;
                int row = 32 * kt + 16 * (j >> 2) + 4 * kg + (j & 3);
                v = (c < 3) ? wc2[row * 3 + c] : 0.0f;
            }
            wp[frag * 512 + lane * 8 + j] = (__bf16)v;
        }
    }
}

__device__ __forceinline__ int bucket_key(float x, float y, float z) {
    int ix = (int)(x * 127.0f); ix = ix < 0 ? 0 : (ix > 127 ? 127 : ix);
    int iy = (int)(y * 127.0f); iy = iy < 0 ? 0 : (iy > 127 ? 127 : iy);
    int iz = (int)(z * 127.0f); iz = iz < 0 ? 0 : (iz > 127 ? 127 : iz);
    return ((ix >> 4) << 6) | ((iy >> 4) << 3) | (iz >> 4);
}

__global__ __launch_bounds__(256) void hist_lds(const float* __restrict__ coords,
                                                unsigned int* __restrict__ mat,
                                                int ppb)
{
    __shared__ unsigned int lh[NBUCKET];
    for (int i = threadIdx.x; i < NBUCKET; i += 256) lh[i] = 0u;
    __syncthreads();
    int base = blockIdx.x * ppb;
    for (int k = threadIdx.x; k < ppb; k += 256) {
        size_t b = 3 * (size_t)(base + k);
        atomicAdd(&lh[bucket_key(coords[b], coords[b + 1], coords[b + 2])], 1u);
    }
    __syncthreads();
    unsigned int* row = mat + (size_t)blockIdx.x * NBUCKET;
    for (int i = threadIdx.x; i < NBUCKET; i += 256) row[i] = lh[i];
}

__global__ __launch_bounds__(256) void col_scan(unsigned int* __restrict__ mat,
                                                unsigned int* __restrict__ total)
{
    int wid  = threadIdx.x >> 6;
    int lane = threadIdx.x & 63;
    int bkt  = blockIdx.x * 4 + wid;

    unsigned int v[4];
#pragma unroll
    for (int j = 0; j < 4; ++j)
        v[j] = mat[(size_t)(lane * 4 + j) * NBUCKET + bkt];
    unsigned int pre[4];
    unsigned int sum = 0;
#pragma unroll
    for (int j = 0; j < 4; ++j) { pre[j] = sum; sum += v[j]; }
    unsigned int inc = sum;
    for (int d = 1; d < 64; d <<= 1) {
        unsigned int u = __shfl_up(inc, d);
        if (lane >= d) inc += u;
    }
    unsigned int excl = inc - sum;
#pragma unroll
    for (int j = 0; j < 4; ++j)
        mat[(size_t)(lane * 4 + j) * NBUCKET + bkt] = excl + pre[j];
    if (lane == 63) total[bkt] = inc;
}

__global__ __launch_bounds__(256) void bucket_scan(const unsigned int* __restrict__ total,
                                                   unsigned int* __restrict__ bbase)
{
    int t = threadIdx.x;
    unsigned int v0 = total[2 * t], v1 = total[2 * t + 1];
    unsigned int run = v0 + v1;
    unsigned int lane = t & 63;
    int wid = t >> 6;
    unsigned int inc = run;
    for (int d = 1; d < 64; d <<= 1) {
        unsigned int u = __shfl_up(inc, d);
        if (lane >= (unsigned)d) inc += u;
    }
    __shared__ unsigned int wt[4];
    if (lane == 63) wt[wid] = inc;
    __syncthreads();
    unsigned int wbase = 0;
    for (int w = 0; w < wid; ++w) wbase += wt[w];
    unsigned int excl = wbase + inc - run;
    bbase[2 * t]     = excl;
    bbase[2 * t + 1] = excl + v0;
}

// scatter: writes ONLY perm (sorted slot -> original index). 8 MB output.
__global__ __launch_bounds__(256) void scatter_perm(const float* __restrict__ coords,
                                                    const unsigned int* __restrict__ mat,
                                                    const unsigned int* __restrict__ bbase,
                                                    int* __restrict__ perm,
                                                    int ppb)
{
    __shared__ unsigned int cur[NBUCKET];
    const unsigned int* row = mat + (size_t)blockIdx.x * NBUCKET;
    for (int i = threadIdx.x; i < NBUCKET; i += 256)
        cur[i] = bbase[i] + row[i];
    __syncthreads();
    int base = blockIdx.x * ppb;
    for (int k = threadIdx.x; k < ppb; k += 256) {
        int i = base + k;
        size_t b = 3 * (size_t)i;
        unsigned int dst = atomicAdd(&cur[bucket_key(coords[b], coords[b + 1], coords[b + 2])], 1u);
        perm[dst] = i;
    }
}

// ---------------------------------------------------------------------------
// Fused NeRF forward: weights-as-A / activations-as-B with co-designed
// K-order packings (all inter-layer handoffs are LOCAL registers).
// Weights in block LDS; coords/ray via perm indirection with a
// 3-deep (perm) / 2-deep (coords,ray) software pipeline.
// ---------------------------------------------------------------------------
__device__ __forceinline__ unsigned int pack2(float a, float b) {
    union { __bf16 h[2]; unsigned int u; } x;
    x.h[0] = (__bf16)a; x.h[1] = (__bf16)b;
    return x.u;
}

union BFU { bf16x8 v; unsigned int u[4]; };

template <bool SORTED>
__global__ __launch_bounds__(256)
__attribute__((amdgpu_waves_per_eu(4)))
void nerf_wave(const float* __restrict__ coords,   // ORIGINAL order
               const float* __restrict__ ray_d,    // ORIGINAL order
               const float* __restrict__ grid,     // [128][128][128][32] f32
               const float* __restrict__ bd1,
               const float* __restrict__ bd2,
               const float* __restrict__ bc1,
               const float* __restrict__ bc2,
               const __bf16* __restrict__ wp,
               const int* __restrict__ perm,       // sorted slot -> original
               float* __restrict__ out,            // [N][4]
               int ntiles)
{
    // LDS: [0,32K) all 32 weight frags (block-shared); then bias tables.
    __shared__ __align__(16) char lds[32768 + 1152];
    float* ldsB1 = (float*)(lds + 32768);   // bd1[128]
    float* ldsB2 = ldsB1 + 128;             // bd2[16]
    float* ldsB3 = ldsB2 + 16;              // bc1[128]
    float* ldsB4 = ldsB3 + 128;             // bc2 padded[16]

    const int tid = threadIdx.x;
    {
        const i32x4* src = (const i32x4*)wp;
        i32x4* dst = (i32x4*)lds;
        for (int i = tid; i < 2048; i += 256) dst[i] = src[i];
        if (tid < 128) ldsB1[tid] = bd1[tid];
        if (tid < 16)  ldsB2[tid] = bd2[tid];
        if (tid < 128) ldsB3[tid] = bc1[tid];
        if (tid < 16)  ldsB4[tid] = (tid < 3) ? bc2[tid] : 0.0f;
    }
    __syncthreads();   // only barrier in the kernel

    const int lane = tid & 63;
    const int wid  = tid >> 6;
    const int c    = lane & 15;
    const int kg   = lane >> 4;
    const int lb   = lane * 16;            // byte offset of lane's frag row
    const int q3   = lane / 3;             // point index for coord loads
    const int e3   = lane - 3 * q3;        // element (x/y/z)

    const int per = (ntiles + gridDim.x - 1) / gridDim.x;
    int sb = blockIdx.x;
    if ((gridDim.x & 7) == 0)
        sb = (blockIdx.x & 7) * (gridDim.x >> 3) + (blockIdx.x >> 3);

    // ---- pipeline prologue: perm 3-deep, coords/ray 2-deep -----------------
    int t0 = sb * per;       if (t0 >= ntiles) t0 = ntiles - 1;
    int t1 = sb * per + 1;   if (t1 >= ntiles) t1 = ntiles - 1;
    int t2 = sb * per + 2;   if (t2 >= ntiles) t2 = ntiles - 1;
    int pvA, pvB, pvC;
    if constexpr (SORTED) {
        pvA = perm[t0 * 64 + wid * 16 + c];
        pvB = perm[t1 * 64 + wid * 16 + c];
        pvC = perm[t2 * 64 + wid * 16 + c];
    } else {
        pvA = t0 * 64 + wid * 16 + c;
        pvB = t1 * 64 + wid * 16 + c;
        pvC = t2 * 64 + wid * 16 + c;
    }
    int pqA = __shfl(pvA, q3);
    int pqB = __shfl(pvB, q3);
    float cvalA = (lane < 48) ? coords[(size_t)pqA * 3 + e3] : 0.0f;
    float rvalA = (lane < 48) ? ray_d[(size_t)pqA * 3 + e3] : 0.0f;
    float cvalB = (lane < 48) ? coords[(size_t)pqB * 3 + e3] : 0.0f;
    float rvalB = (lane < 48) ? ray_d[(size_t)pqB * 3 + e3] : 0.0f;

    for (int it = 0; it < per; ++it) {
        const int tile = sb * per + it;
        if (tile >= ntiles) break;

        // ---- coords of this lane's point c (pipelined, 2 iters of slack) --
        float cx = __shfl(cvalA, 3 * c + 0) * 127.0f;
        float cy = __shfl(cvalA, 3 * c + 1) * 127.0f;
        float cz = __shfl(cvalA, 3 * c + 2) * 127.0f;
        int ix = (int)floorf(cx); ix = ix < 0 ? 0 : (ix > 126 ? 126 : ix);
        int iy = (int)floorf(cy); iy = iy < 0 ? 0 : (iy > 126 ? 126 : iy);
        int iz = (int)floorf(cz); iz = iz < 0 ? 0 : (iz > 126 ? 126 : iz);
        float tx = cx - (float)ix;
        float ty = cy - (float)iy;
        float tz = cz - (float)iz;

        // ---- gather: feats[kg*8 .. kg*8+7] of point c (B-frag layout) -----
        f32x4 fa = {0.0f, 0.0f, 0.0f, 0.0f};
        f32x4 fb = {0.0f, 0.0f, 0.0f, 0.0f};
#pragma unroll
        for (int cc = 0; cc < 8; ++cc) {
            int ddx = (cc >> 2) & 1, ddy = (cc >> 1) & 1, ddz = cc & 1;
            float w = (ddx ? tx : 1.0f - tx) *
                      (ddy ? ty : 1.0f - ty) *
                      (ddz ? tz : 1.0f - tz);
            int idx = ((ix + ddx) << 14) + ((iy + ddy) << 7) + (iz + ddz);
            const f32x4* g = (const f32x4*)(grid + (size_t)idx * 32 + kg * 8);
            f32x4 v0 = g[0], v1 = g[1];
#pragma unroll
            for (int e = 0; e < 4; ++e) {
                fa[e] = fmaf(w, v0[e], fa[e]);
                fb[e] = fmaf(w, v1[e], fb[e]);
            }
        }
        BFU b0;
        b0.u[0] = pack2(fa[0], fa[1]); b0.u[1] = pack2(fa[2], fa[3]);
        b0.u[2] = pack2(fb[0], fb[1]); b0.u[3] = pack2(fb[2], fb[3]);

        // ---- prefetch tile+2 coords/ray (2 iters ahead) + tile+3 perm -----
        float cvalC, rvalC;
        int pvD;
        {
            int pqC = __shfl(pvC, q3);          // pvC loaded 1 iter ago
            cvalC = (lane < 48) ? coords[(size_t)pqC * 3 + e3] : 0.0f;
            rvalC = (lane < 48) ? ray_d[(size_t)pqC * 3 + e3] : 0.0f;
            int t3 = tile + 3; if (t3 >= ntiles) t3 = ntiles - 1;
            if constexpr (SORTED) pvD = perm[t3 * 64 + wid * 16 + c];
            else                  pvD = t3 * 64 + wid * 16 + c;
        }

        // ---- view embedding slots for this lane (dims fixed by kg) --------
        float dxv = __shfl(rvalA, 3 * c + 0);
        float dyv = __shfl(rvalA, 3 * c + 1);
        float dzv = __shfl(rvalA, 3 * c + 2);
        float E0, E1, E2, E3, G0, G1, G2, G3, G4, G5, G6, G7;
        if (kg == 0) {            // E: dims 16-19, G: dims 32-39
            E0 = dxv; E1 = dyv; E2 = dzv; E3 = __sinf(dxv);
            G0 = __cosf(dyv);        G1 = __cosf(dzv);
            G2 = __cosf(2.0f * dxv); G3 = __cosf(2.0f * dyv);
            G4 = __cosf(2.0f * dzv); G5 = __cosf(4.0f * dxv);
            G6 = __cosf(4.0f * dyv); G7 = __cosf(4.0f * dzv);
        } else if (kg == 1) {     // E: dims 20-23, G: dims 40-42 + zeros
            E0 = __sinf(dyv);        E1 = __sinf(dzv);
            E2 = __sinf(2.0f * dxv); E3 = __sinf(2.0f * dyv);
            G0 = __cosf(8.0f * dxv); G1 = __cosf(8.0f * dyv);
            G2 = __cosf(8.0f * dzv);
            G3 = 0.0f; G4 = 0.0f; G5 = 0.0f; G6 = 0.0f; G7 = 0.0f;
        } else if (kg == 2) {     // E: dims 24-27, G: zeros
            E0 = __sinf(2.0f * dzv); E1 = __sinf(4.0f * dxv);
            E2 = __sinf(4.0f * dyv); E3 = __sinf(4.0f * dzv);
            G0 = G1 = G2 = G3 = G4 = G5 = G6 = G7 = 0.0f;
        } else {                  // E: dims 28-31, G: zeros
            E0 = __sinf(8.0f * dxv); E1 = __sinf(8.0f * dyv);
            E2 = __sinf(8.0f * dzv); E3 = __cosf(dxv);
            G0 = G1 = G2 = G3 = G4 = G5 = G6 = G7 = 0.0f;
        }

        // ---- L1: h[16n+4kg+i][c] = wd1^T . feats + bd1 --------------------
        f32x4 acc[8];
#pragma unroll
        for (int n = 0; n < 8; ++n) {
            f32x4 bi = *(const f32x4*)(ldsB1 + n * 16 + kg * 4);
            bf16x8 A = *(const bf16x8*)(lds + n * 1024 + lb);
            acc[n] = __builtin_amdgcn_mfma_f32_16x16x32_bf16(A, b0.v, bi, 0, 0, 0);
        }
        unsigned int pk[8][2];
#pragma unroll
        for (int n = 0; n < 8; ++n) {
            pk[n][0] = pack2(fmaxf(acc[n][0], 0.0f), fmaxf(acc[n][1], 0.0f));
            pk[n][1] = pack2(fmaxf(acc[n][2], 0.0f), fmaxf(acc[n][3], 0.0f));
        }

        // ---- L2: dfeat[4kg+i][c]; split into 2 parallel chains ------------
        f32x4 a2A = *(const f32x4*)(ldsB2 + kg * 4);
        f32x4 a2B = {0.0f, 0.0f, 0.0f, 0.0f};
#pragma unroll
        for (int kt = 0; kt < 4; ++kt) {
            BFU B;
            B.u[0] = pk[2 * kt][0];     B.u[1] = pk[2 * kt][1];
            B.u[2] = pk[2 * kt + 1][0]; B.u[3] = pk[2 * kt + 1][1];
            bf16x8 A = *(const bf16x8*)(lds + (8 + kt) * 1024 + lb);
            if (kt & 1) a2B = __builtin_amdgcn_mfma_f32_16x16x32_bf16(A, B.v, a2B, 0, 0, 0);
            else        a2A = __builtin_amdgcn_mfma_f32_16x16x32_bf16(A, B.v, a2A, 0, 0, 0);
        }
        f32x4 accd = a2A + a2B;
        float dens = fmaxf(accd[0], 0.0f);   // dfeat[0]: valid on kg==0 lanes

        // ---- L3: B(kt3=0) = {dfeat local, E}, B(kt3=1) = {G} --------------
        BFU Bk0, Bk1;
        Bk0.u[0] = pack2(accd[0], accd[1]);
        Bk0.u[1] = pack2(accd[2], accd[3]);
        Bk0.u[2] = pack2(E0, E1);
        Bk0.u[3] = pack2(E2, E3);
        Bk1.u[0] = pack2(G0, G1);
        Bk1.u[1] = pack2(G2, G3);
        Bk1.u[2] = pack2(G4, G5);
        Bk1.u[3] = pack2(G6, G7);

        f32x4 acc3[8];
#pragma unroll
        for (int n = 0; n < 8; ++n) {
            f32x4 bi = *(const f32x4*)(ldsB3 + n * 16 + kg * 4);
            bf16x8 w0 = *(const bf16x8*)(lds + (12 + n * 2 + 0) * 1024 + lb);
            bf16x8 w1 = *(const bf16x8*)(lds + (12 + n * 2 + 1) * 1024 + lb);
            acc3[n] = __builtin_amdgcn_mfma_f32_16x16x32_bf16(w0, Bk0.v, bi, 0, 0, 0);
            acc3[n] = __builtin_amdgcn_mfma_f32_16x16x32_bf16(w1, Bk1.v, acc3[n], 0, 0, 0);
        }
        unsigned int pk3[8][2];
#pragma unroll
        for (int n = 0; n < 8; ++n) {
            pk3[n][0] = pack2(fmaxf(acc3[n][0], 0.0f), fmaxf(acc3[n][1], 0.0f));
            pk3[n][1] = pack2(fmaxf(acc3[n][2], 0.0f), fmaxf(acc3[n][3], 0.0f));
        }

        // ---- L4: rgb[4kg+i][c]; split into 2 parallel chains --------------
        f32x4 a4A = *(const f32x4*)(ldsB4 + kg * 4);
        f32x4 a4B = {0.0f, 0.0f, 0.0f, 0.0f};
#pragma unroll
        for (int kt = 0; kt < 4; ++kt) {
            BFU B;
            B.u[0] = pk3[2 * kt][0];     B.u[1] = pk3[2 * kt][1];
            B.u[2] = pk3[2 * kt + 1][0]; B.u[3] = pk3[2 * kt + 1][1];
            bf16x8 A = *(const bf16x8*)(lds + (28 + kt) * 1024 + lb);
            if (kt & 1) a4B = __builtin_amdgcn_mfma_f32_16x16x32_bf16(A, B.v, a4B, 0, 0, 0);
            else        a4A = __builtin_amdgcn_mfma_f32_16x16x32_bf16(A, B.v, a4A, 0, 0, 0);
        }
        f32x4 acco = a4A + a4B;

        // ---- store: lane (kg==0, c) owns point c completely ---------------
        if (lane < 16) {
            f32x4 o;
            o[0] = 1.0f / (1.0f + __expf(-acco[0]));
            o[1] = 1.0f / (1.0f + __expf(-acco[1]));
            o[2] = 1.0f / (1.0f + __expf(-acco[2]));
            o[3] = dens;
            ((f32x4*)out)[pvA] = o;
        }

        // ---- rotate pipeline ----------------------------------------------
        cvalA = cvalB; rvalA = rvalB;
        cvalB = cvalC; rvalB = rvalC;
        pvA = pvB; pvB = pvC; pvC = pvD;
    }
}

extern "C" void kernel_launch(void* const* d_in, const int* in_sizes, int n_in,
                              void* d_out, int out_size, void* d_ws, size_t ws_size,
                              hipStream_t stream) {
    const float* coords = (const float*)d_in[0];
    const float* ray_d  = (const float*)d_in[1];
    const float* grid   = (const float*)d_in[2];
    const float* wd1    = (const float*)d_in[3];
    const float* bd1    = (const float*)d_in[4];
    const float* wd2    = (const float*)d_in[5];
    const float* bd2    = (const float*)d_in[6];
    const float* wc1    = (const float*)d_in[7];
    const float* bc1    = (const float*)d_in[8];
    const float* wc2    = (const float*)d_in[9];
    const float* bc2    = (const float*)d_in[10];
    float* out = (float*)d_out;

    int N = in_sizes[0] / 3;
    int ntiles = N >> 6;

    char* ws = (char*)d_ws;
    __bf16* wp = (__bf16*)(ws + WS_WP);

    pack_weights<<<1, 256, 0, stream>>>(wd1, wd2, wc1, wc2, wp);

    int blocks = ntiles < 8192 ? ntiles : 8192;

    if (ws_size >= WS_NEED && (N % (HB * 64)) == 0) {
        unsigned int* mat   = (unsigned int*)(ws + WS_MAT);
        unsigned int* total = (unsigned int*)(ws + WS_TOT);
        unsigned int* bbase = (unsigned int*)(ws + WS_BB);
        int* perm = (int*)(ws + WS_PERM);
        int ppb = N / HB;

        hist_lds<<<HB, 256, 0, stream>>>(coords, mat, ppb);
        col_scan<<<NBUCKET / 4, 256, 0, stream>>>(mat, total);
        bucket_scan<<<1, 256, 0, stream>>>(total, bbase);
        scatter_perm<<<HB, 256, 0, stream>>>(coords, mat, bbase, perm, ppb);
        nerf_wave<true><<<blocks, 256, 0, stream>>>(coords, ray_d, grid,
                                                    bd1, bd2, bc1, bc2,
                                                    wp, perm, out, ntiles);
    } else {
        nerf_wave<false><<<blocks, 256, 0, stream>>>(coords, ray_d, grid,
                                                     bd1, bd2, bc1, bc2,
                                                     wp, nullptr, out, ntiles);
    }
}

// Round 13
// 396.867 us; speedup vs baseline: 2.5317x; 1.0172x over previous
//
#include <hip/hip_runtime.h>
#include <hip/hip_bf16.h>
#include <math.h>

typedef __attribute__((ext_vector_type(8))) __bf16 bf16x8;
typedef __attribute__((ext_vector_type(4))) float f32x4;
typedef __attribute__((ext_vector_type(4))) int i32x4;

// ---- sort configuration ---------------------------------------------------
#define NBUCKET 512            // 8x8x8 regions of 16^3 cells
#define HB      256            // histogram blocks
// workspace layout (bytes) -- record-based sort output
#define WS_WP   0UL                    // packed weights     32 KB
#define WS_MAT  32768UL                // [HB][NBUCKET] u32  512 KB
#define WS_TOT  557056UL               // 512 u32
#define WS_BB   559104UL               // 512 u32
#define WS_REC  561152UL               // rec[N] 32 B        64 MB
#define WS_NEED 67670016UL

// ---------------------------------------------------------------------------
// Pack MLP weights into MFMA A-fragment layout (weights-as-A).
// Frag f: 1024 B; lane l supplies A[m = l&15][kpos = (l>>4)*8 + j].
//   frags 0-7  : wd1, K-order identity          (out-frag n)
//   frags 8-11 : wd2, K-order PERMUTED          (K-tile kt)
//   frags 12-27: wc1, K-order = F-layout        (out-frag f3, kt3 = frag&1)
//   frags 28-31: wc2, K-order PERMUTED          (K-tile kt)
// PERMUTED K-row for (kt,kg,j): row = 32kt + 16(j>>2) + 4kg + (j&3) --
// makes the previous layer's D-layout directly usable as B-fragments.
// F-layout rows (L3): kt3=0,j<4 -> dfeat 4kg+j ; kt3=0,j>=4 -> view
// 16+4kg+(j-4) ; kt3=1 -> view 32+8kg+j (rows >42 zero).
// ---------------------------------------------------------------------------
__global__ void pack_weights(const float* __restrict__ wd1,
                             const float* __restrict__ wd2,
                             const float* __restrict__ wc1,
                             const float* __restrict__ wc2,
                             __bf16* __restrict__ wp)
{
    int t0 = threadIdx.x;
    for (int it = 0; it < 8; ++it) {
        int t = it * 256 + t0;
        int frag = t >> 6;
        int lane = t & 63;
        int kg = lane >> 4;
        int c  = lane & 15;
        for (int j = 0; j < 8; ++j) {
            float v;
            if (frag < 8) {
                int k = kg * 8 + j;
                v = wd1[k * 128 + frag * 16 + c];
            } else if (frag < 12) {
                int kt = frag - 8;
                int row = 32 * kt + 16 * (j >> 2) + 4 * kg + (j & 3);
                v = wd2[row * 16 + c];
            } else if (frag < 28) {
                int f = frag - 12;
                int f3 = f >> 1, kt3 = f & 1;
                int row;
                if (kt3 == 0) row = (j < 4) ? (4 * kg + j) : (16 + 4 * kg + (j - 4));
                else          row = 32 + 8 * kg + j;
                v = (row < 43) ? wc1[row * 128 + f3 * 16 + c] : 0.0f;
            } else {
                int kt = frag - 28;
                int row = 32 * kt + 16 * (j >> 2) + 4 * kg + (j & 3);
                v = (c < 3) ? wc2[row * 3 + c] : 0.0f;
            }
            wp[frag * 512 + lane * 8 + j] = (__bf16)v;
        }
    }
}

__device__ __forceinline__ int bucket_key(float x, float y, float z) {
    int ix = (int)(x * 127.0f); ix = ix < 0 ? 0 : (ix > 127 ? 127 : ix);
    int iy = (int)(y * 127.0f); iy = iy < 0 ? 0 : (iy > 127 ? 127 : iy);
    int iz = (int)(z * 127.0f); iz = iz < 0 ? 0 : (iz > 127 ? 127 : iz);
    return ((ix >> 4) << 6) | ((iy >> 4) << 3) | (iz >> 4);
}

__global__ __launch_bounds__(256) void hist_lds(const float* __restrict__ coords,
                                                unsigned int* __restrict__ mat,
                                                int ppb)
{
    __shared__ unsigned int lh[NBUCKET];
    for (int i = threadIdx.x; i < NBUCKET; i += 256) lh[i] = 0u;
    __syncthreads();
    int base = blockIdx.x * ppb;
    for (int k = threadIdx.x; k < ppb; k += 256) {
        size_t b = 3 * (size_t)(base + k);
        atomicAdd(&lh[bucket_key(coords[b], coords[b + 1], coords[b + 2])], 1u);
    }
    __syncthreads();
    unsigned int* row = mat + (size_t)blockIdx.x * NBUCKET;
    for (int i = threadIdx.x; i < NBUCKET; i += 256) row[i] = lh[i];
}

__global__ __launch_bounds__(256) void col_scan(unsigned int* __restrict__ mat,
                                                unsigned int* __restrict__ total)
{
    int wid  = threadIdx.x >> 6;
    int lane = threadIdx.x & 63;
    int bkt  = blockIdx.x * 4 + wid;

    unsigned int v[4];
#pragma unroll
    for (int j = 0; j < 4; ++j)
        v[j] = mat[(size_t)(lane * 4 + j) * NBUCKET + bkt];
    unsigned int pre[4];
    unsigned int sum = 0;
#pragma unroll
    for (int j = 0; j < 4; ++j) { pre[j] = sum; sum += v[j]; }
    unsigned int inc = sum;
    for (int d = 1; d < 64; d <<= 1) {
        unsigned int u = __shfl_up(inc, d);
        if (lane >= d) inc += u;
    }
    unsigned int excl = inc - sum;
#pragma unroll
    for (int j = 0; j < 4; ++j)
        mat[(size_t)(lane * 4 + j) * NBUCKET + bkt] = excl + pre[j];
    if (lane == 63) total[bkt] = inc;
}

__global__ __launch_bounds__(256) void bucket_scan(const unsigned int* __restrict__ total,
                                                   unsigned int* __restrict__ bbase)
{
    int t = threadIdx.x;
    unsigned int v0 = total[2 * t], v1 = total[2 * t + 1];
    unsigned int run = v0 + v1;
    unsigned int lane = t & 63;
    int wid = t >> 6;
    unsigned int inc = run;
    for (int d = 1; d < 64; d <<= 1) {
        unsigned int u = __shfl_up(inc, d);
        if (lane >= (unsigned)d) inc += u;
    }
    __shared__ unsigned int wt[4];
    if (lane == 63) wt[wid] = inc;
    __syncthreads();
    unsigned int wbase = 0;
    for (int w = 0; w < wid; ++w) wbase += wt[w];
    unsigned int excl = wbase + inc - run;
    bbase[2 * t]     = excl;
    bbase[2 * t + 1] = excl + v0;
}

// scatter: writes packed 32-B records {x,y,z,dx, dy,dz,idx,0} in sorted order.
__global__ __launch_bounds__(256) void scatter_rec(const float* __restrict__ coords,
                                                   const float* __restrict__ rayd,
                                                   const unsigned int* __restrict__ mat,
                                                   const unsigned int* __restrict__ bbase,
                                                   float* __restrict__ rec,
                                                   int ppb)
{
    __shared__ unsigned int cur[NBUCKET];
    const unsigned int* row = mat + (size_t)blockIdx.x * NBUCKET;
    for (int i = threadIdx.x; i < NBUCKET; i += 256)
        cur[i] = bbase[i] + row[i];
    __syncthreads();
    int base = blockIdx.x * ppb;
    for (int k = threadIdx.x; k < ppb; k += 256) {
        int i = base + k;
        size_t b = 3 * (size_t)i;
        float x = coords[b], y = coords[b + 1], z = coords[b + 2];
        unsigned int dst = atomicAdd(&cur[bucket_key(x, y, z)], 1u);
        f32x4 r0 = {x, y, z, rayd[b]};
        f32x4 r1 = {rayd[b + 1], rayd[b + 2], __int_as_float(i), 0.0f};
        f32x4* rp = (f32x4*)rec + (size_t)dst * 2;
        rp[0] = r0;
        rp[1] = r1;
    }
}

// ---------------------------------------------------------------------------
// Fused NeRF forward: weights-as-A / activations-as-B with co-designed
// K-order packings (all inter-layer handoffs are LOCAL registers).
// 512-thread blocks: 8 waves share one 32 KB LDS weight copy ->
// 4 blocks/CU x 8 waves = 32 waves/CU occupancy cap (VGPR ~60 allows it).
// Sorted path reads ONE coalesced 32-B record per point; store via
// embedded original index. View embedding: 6 transcendentals + doubling.
// ---------------------------------------------------------------------------
__device__ __forceinline__ unsigned int pack2(float a, float b) {
    union { __bf16 h[2]; unsigned int u; } x;
    x.h[0] = (__bf16)a; x.h[1] = (__bf16)b;
    return x.u;
}

union BFU { bf16x8 v; unsigned int u[4]; };

template <bool SORTED>
__global__ __launch_bounds__(512)
void nerf_wave(const float* __restrict__ coords,   // used if !SORTED
               const float* __restrict__ ray_d,    // used if !SORTED
               const float* __restrict__ grid,     // [128][128][128][32] f32
               const float* __restrict__ bd1,
               const float* __restrict__ bd2,
               const float* __restrict__ bc1,
               const float* __restrict__ bc2,
               const __bf16* __restrict__ wp,
               const float* __restrict__ rec,      // sorted records if SORTED
               float* __restrict__ out,            // [N][4]
               int ntiles)                         // 128-point tiles
{
    // LDS: [0,32K) all 32 weight frags (block-shared); then bias tables.
    __shared__ __align__(16) char lds[32768 + 1152];
    float* ldsB1 = (float*)(lds + 32768);   // bd1[128]
    float* ldsB2 = ldsB1 + 128;             // bd2[16]
    float* ldsB3 = ldsB2 + 16;              // bc1[128]
    float* ldsB4 = ldsB3 + 128;             // bc2 padded[16]

    const int tid = threadIdx.x;
    {
        const i32x4* src = (const i32x4*)wp;
        i32x4* dst = (i32x4*)lds;
        for (int i = tid; i < 2048; i += 512) dst[i] = src[i];
        if (tid < 128) ldsB1[tid] = bd1[tid];
        if (tid < 16)  ldsB2[tid] = bd2[tid];
        if (tid < 128) ldsB3[tid] = bc1[tid];
        if (tid < 16)  ldsB4[tid] = (tid < 3) ? bc2[tid] : 0.0f;
    }
    __syncthreads();   // only barrier in the kernel

    const int lane = tid & 63;
    const int wid  = tid >> 6;             // 0..7
    const int c    = lane & 15;
    const int kg   = lane >> 4;
    const int lb   = lane * 16;            // byte offset of lane's frag row
    const int rsub = (lane >> 4) & 1;      // record half this lane loads

    const int per = (ntiles + gridDim.x - 1) / gridDim.x;
    int sb = blockIdx.x;
    if ((gridDim.x & 7) == 0)
        sb = (blockIdx.x & 7) * (gridDim.x >> 3) + (blockIdx.x >> 3);

    // ---- prologue: load iteration-0 records ---------------------------------
    f32x4 recA = {0.0f, 0.0f, 0.0f, 0.0f};
    if constexpr (SORTED) {
        int t0 = sb * per; if (t0 >= ntiles) t0 = ntiles - 1;
        recA = ((const f32x4*)rec)[(size_t)(t0 * 128 + wid * 16 + (lane & 15)) * 2 + rsub];
    }

    for (int it = 0; it < per; ++it) {
        const int tile = sb * per + it;
        if (tile >= ntiles) break;

        // ---- extract this lane's point: coords, ray, output index ---------
        float px, py, pz, dxv, dyv, dzv;
        int pv;
        if constexpr (SORTED) {
            px  = __shfl(recA[0], c) * 127.0f;
            py  = __shfl(recA[1], c) * 127.0f;
            pz  = __shfl(recA[2], c) * 127.0f;
            dxv = __shfl(recA[3], c);
            dyv = __shfl(recA[0], 16 + c);
            dzv = __shfl(recA[1], 16 + c);
            pv  = __float_as_int(__shfl(recA[2], 16 + c));
        } else {
            int pw = tile * 128 + wid * 16;
            float cval = (lane < 48) ? coords[(size_t)pw * 3 + lane] : 0.0f;
            float rval = (lane < 48) ? ray_d[(size_t)pw * 3 + lane] : 0.0f;
            px  = __shfl(cval, 3 * c + 0) * 127.0f;
            py  = __shfl(cval, 3 * c + 1) * 127.0f;
            pz  = __shfl(cval, 3 * c + 2) * 127.0f;
            dxv = __shfl(rval, 3 * c + 0);
            dyv = __shfl(rval, 3 * c + 1);
            dzv = __shfl(rval, 3 * c + 2);
            pv  = pw + c;
        }
        int ix = (int)floorf(px); ix = ix < 0 ? 0 : (ix > 126 ? 126 : ix);
        int iy = (int)floorf(py); iy = iy < 0 ? 0 : (iy > 126 ? 126 : iy);
        int iz = (int)floorf(pz); iz = iz < 0 ? 0 : (iz > 126 ? 126 : iz);
        float tx = px - (float)ix;
        float ty = py - (float)iy;
        float tz = pz - (float)iz;

        // ---- gather: feats[kg*8 .. kg*8+7] of point c (B-frag layout) -----
        f32x4 fa = {0.0f, 0.0f, 0.0f, 0.0f};
        f32x4 fb = {0.0f, 0.0f, 0.0f, 0.0f};
#pragma unroll
        for (int cc = 0; cc < 8; ++cc) {
            int ddx = (cc >> 2) & 1, ddy = (cc >> 1) & 1, ddz = cc & 1;
            float w = (ddx ? tx : 1.0f - tx) *
                      (ddy ? ty : 1.0f - ty) *
                      (ddz ? tz : 1.0f - tz);
            int idx = ((ix + ddx) << 14) + ((iy + ddy) << 7) + (iz + ddz);
            const f32x4* g = (const f32x4*)(grid + (size_t)idx * 32 + kg * 8);
            f32x4 v0 = g[0], v1 = g[1];
#pragma unroll
            for (int e = 0; e < 4; ++e) {
                fa[e] = fmaf(w, v0[e], fa[e]);
                fb[e] = fmaf(w, v1[e], fb[e]);
            }
        }
        BFU b0;
        b0.u[0] = pack2(fa[0], fa[1]); b0.u[1] = pack2(fa[2], fa[3]);
        b0.u[2] = pack2(fb[0], fb[1]); b0.u[3] = pack2(fb[2], fb[3]);

        // ---- prefetch next tile's records (overlaps MLP below) ------------
        f32x4 recB = recA;
        if constexpr (SORTED) {
            int tn = tile + 1; if (tn >= ntiles) tn = ntiles - 1;
            recB = ((const f32x4*)rec)[(size_t)(tn * 128 + wid * 16 + (lane & 15)) * 2 + rsub];
        }

        // ---- view embedding: 6 transcendentals + angle doubling -----------
        float s1x = __sinf(dxv), c1x = __cosf(dxv);
        float s1y = __sinf(dyv), c1y = __cosf(dyv);
        float s1z = __sinf(dzv), c1z = __cosf(dzv);
        float s2x = 2.0f * s1x * c1x, c2x = fmaf(-2.0f * s1x, s1x, 1.0f);
        float s2y = 2.0f * s1y * c1y, c2y = fmaf(-2.0f * s1y, s1y, 1.0f);
        float s2z = 2.0f * s1z * c1z, c2z = fmaf(-2.0f * s1z, s1z, 1.0f);
        float s4x = 2.0f * s2x * c2x, c4x = fmaf(-2.0f * s2x, s2x, 1.0f);
        float s4y = 2.0f * s2y * c2y, c4y = fmaf(-2.0f * s2y, s2y, 1.0f);
        float s4z = 2.0f * s2z * c2z, c4z = fmaf(-2.0f * s2z, s2z, 1.0f);
        float s8x = 2.0f * s4x * c4x, c8x = fmaf(-2.0f * s4x, s4x, 1.0f);
        float s8y = 2.0f * s4y * c4y, c8y = fmaf(-2.0f * s4y, s4y, 1.0f);
        float s8z = 2.0f * s4z * c4z, c8z = fmaf(-2.0f * s4z, s4z, 1.0f);

        float E0, E1, E2, E3, G0, G1, G2, G3, G4, G5, G6, G7;
        if (kg == 0) {            // E: dims 16-19, G: dims 32-39
            E0 = dxv; E1 = dyv; E2 = dzv; E3 = s1x;
            G0 = c1y; G1 = c1z; G2 = c2x; G3 = c2y;
            G4 = c2z; G5 = c4x; G6 = c4y; G7 = c4z;
        } else if (kg == 1) {     // E: dims 20-23, G: dims 40-42 + zeros
            E0 = s1y; E1 = s1z; E2 = s2x; E3 = s2y;
            G0 = c8x; G1 = c8y; G2 = c8z;
            G3 = 0.0f; G4 = 0.0f; G5 = 0.0f; G6 = 0.0f; G7 = 0.0f;
        } else if (kg == 2) {     // E: dims 24-27, G: zeros
            E0 = s2z; E1 = s4x; E2 = s4y; E3 = s4z;
            G0 = G1 = G2 = G3 = G4 = G5 = G6 = G7 = 0.0f;
        } else {                  // E: dims 28-31, G: zeros
            E0 = s8x; E1 = s8y; E2 = s8z; E3 = c1x;
            G0 = G1 = G2 = G3 = G4 = G5 = G6 = G7 = 0.0f;
        }

        // ---- L1: h[16n+4kg+i][c] = wd1^T . feats + bd1 --------------------
        f32x4 acc[8];
#pragma unroll
        for (int n = 0; n < 8; ++n) {
            f32x4 bi = *(const f32x4*)(ldsB1 + n * 16 + kg * 4);
            bf16x8 A = *(const bf16x8*)(lds + n * 1024 + lb);
            acc[n] = __builtin_amdgcn_mfma_f32_16x16x32_bf16(A, b0.v, bi, 0, 0, 0);
        }
        unsigned int pk[8][2];
#pragma unroll
        for (int n = 0; n < 8; ++n) {
            pk[n][0] = pack2(fmaxf(acc[n][0], 0.0f), fmaxf(acc[n][1], 0.0f));
            pk[n][1] = pack2(fmaxf(acc[n][2], 0.0f), fmaxf(acc[n][3], 0.0f));
        }

        // ---- L2: dfeat[4kg+i][c]; split into 2 parallel chains ------------
        f32x4 a2A = *(const f32x4*)(ldsB2 + kg * 4);
        f32x4 a2B = {0.0f, 0.0f, 0.0f, 0.0f};
#pragma unroll
        for (int kt = 0; kt < 4; ++kt) {
            BFU B;
            B.u[0] = pk[2 * kt][0];     B.u[1] = pk[2 * kt][1];
            B.u[2] = pk[2 * kt + 1][0]; B.u[3] = pk[2 * kt + 1][1];
            bf16x8 A = *(const bf16x8*)(lds + (8 + kt) * 1024 + lb);
            if (kt & 1) a2B = __builtin_amdgcn_mfma_f32_16x16x32_bf16(A, B.v, a2B, 0, 0, 0);
            else        a2A = __builtin_amdgcn_mfma_f32_16x16x32_bf16(A, B.v, a2A, 0, 0, 0);
        }
        f32x4 accd = a2A + a2B;
        float dens = fmaxf(accd[0], 0.0f);   // dfeat[0]: valid on kg==0 lanes

        // ---- L3: B(kt3=0) = {dfeat local, E}, B(kt3=1) = {G} --------------
        BFU Bk0, Bk1;
        Bk0.u[0] = pack2(accd[0], accd[1]);
        Bk0.u[1] = pack2(accd[2], accd[3]);
        Bk0.u[2] = pack2(E0, E1);
        Bk0.u[3] = pack2(E2, E3);
        Bk1.u[0] = pack2(G0, G1);
        Bk1.u[1] = pack2(G2, G3);
        Bk1.u[2] = pack2(G4, G5);
        Bk1.u[3] = pack2(G6, G7);

        f32x4 acc3[8];
#pragma unroll
        for (int n = 0; n < 8; ++n) {
            f32x4 bi = *(const f32x4*)(ldsB3 + n * 16 + kg * 4);
            bf16x8 w0 = *(const bf16x8*)(lds + (12 + n * 2 + 0) * 1024 + lb);
            bf16x8 w1 = *(const bf16x8*)(lds + (12 + n * 2 + 1) * 1024 + lb);
            acc3[n] = __builtin_amdgcn_mfma_f32_16x16x32_bf16(w0, Bk0.v, bi, 0, 0, 0);
            acc3[n] = __builtin_amdgcn_mfma_f32_16x16x32_bf16(w1, Bk1.v, acc3[n], 0, 0, 0);
        }
        unsigned int pk3[8][2];
#pragma unroll
        for (int n = 0; n < 8; ++n) {
            pk3[n][0] = pack2(fmaxf(acc3[n][0], 0.0f), fmaxf(acc3[n][1], 0.0f));
            pk3[n][1] = pack2(fmaxf(acc3[n][2], 0.0f), fmaxf(acc3[n][3], 0.0f));
        }

        // ---- L4: rgb[4kg+i][c]; split into 2 parallel chains --------------
        f32x4 a4A = *(const f32x4*)(ldsB4 + kg * 4);
        f32x4 a4B = {0.0f, 0.0f, 0.0f, 0.0f};
#pragma unroll
        for (int kt = 0; kt < 4; ++kt) {
            BFU B;
            B.u[0] = pk3[2 * kt][0];     B.u[1] = pk3[2 * kt][1];
            B.u[2] = pk3[2 * kt + 1][0]; B.u[3] = pk3[2 * kt + 1][1];
            bf16x8 A = *(const bf16x8*)(lds + (28 + kt) * 1024 + lb);
            if (kt & 1) a4B = __builtin_amdgcn_mfma_f32_16x16x32_bf16(A, B.v, a4B, 0, 0, 0);
            else        a4A = __builtin_amdgcn_mfma_f32_16x16x32_bf16(A, B.v, a4A, 0, 0, 0);
        }
        f32x4 acco = a4A + a4B;

        // ---- store: lane (kg==0, c) owns point c completely ---------------
        if (lane < 16) {
            f32x4 o;
            o[0] = 1.0f / (1.0f + __expf(-acco[0]));
            o[1] = 1.0f / (1.0f + __expf(-acco[1]));
            o[2] = 1.0f / (1.0f + __expf(-acco[2]));
            o[3] = dens;
            ((f32x4*)out)[pv] = o;
        }

        recA = recB;
    }
}

extern "C" void kernel_launch(void* const* d_in, const int* in_sizes, int n_in,
                              void* d_out, int out_size, void* d_ws, size_t ws_size,
                              hipStream_t stream) {
    const float* coords = (const float*)d_in[0];
    const float* ray_d  = (const float*)d_in[1];
    const float* grid   = (const float*)d_in[2];
    const float* wd1    = (const float*)d_in[3];
    const float* bd1    = (const float*)d_in[4];
    const float* wd2    = (const float*)d_in[5];
    const float* bd2    = (const float*)d_in[6];
    const float* wc1    = (const float*)d_in[7];
    const float* bc1    = (const float*)d_in[8];
    const float* wc2    = (const float*)d_in[9];
    const float* bc2    = (const float*)d_in[10];
    float* out = (float*)d_out;

    int N = in_sizes[0] / 3;
    int ntiles = N >> 7;                    // 128-point tiles

    char* ws = (char*)d_ws;
    __bf16* wp = (__bf16*)(ws + WS_WP);

    pack_weights<<<1, 256, 0, stream>>>(wd1, wd2, wc1, wc2, wp);

    int blocks = ntiles < 2048 ? ntiles : 2048;

    if (ws_size >= WS_NEED && (N % (HB * 128)) == 0) {
        unsigned int* mat   = (unsigned int*)(ws + WS_MAT);
        unsigned int* total = (unsigned int*)(ws + WS_TOT);
        unsigned int* bbase = (unsigned int*)(ws + WS_BB);
        float* rec = (float*)(ws + WS_REC);
        int ppb = N / HB;

        hist_lds<<<HB, 256, 0, stream>>>(coords, mat, ppb);
        col_scan<<<NBUCKET / 4, 256, 0, stream>>>(mat, total);
        bucket_scan<<<1, 256, 0, stream>>>(total, bbase);
        scatter_rec<<<HB, 256, 0, stream>>>(coords, ray_d, mat, bbase, rec, ppb);
        nerf_wave<true><<<blocks, 512, 0, stream>>>(coords, ray_d, grid,
                                                    bd1, bd2, bc1, bc2,
                                                    wp, rec, out, ntiles);
    } else {
        nerf_wave<false><<<blocks, 512, 0, stream>>>(coords, ray_d, grid,
                                                     bd1, bd2, bc1, bc2,
                                                     wp, nullptr, out, ntiles);
    }
}